// Round 3
// baseline (135.795 us; speedup 1.0000x reference)
//
#include <hip/hip_runtime.h>

// Fully-fused SepConv on sphere, round 3.
// Algebra (verified absmax 0.0 in R2): the whole chain
//   x -> *qw -> DISCO(K=4,9tap) -> depth-mix -> *qw -> DISCO(K=1,4tap) -> 1x1
// composes into one 5x5 clip/wrap stencil with per-(c,h) coefs C[c][25]
// (C = w_depth . S, S[4][25] channel-independent), then a 32->64 GEMV.
//
// R3 changes (latency-bound fix): float4 loads + 4-px register blocking,
// 4-way channel split with LDS z-exchange, XCD-contiguous block swizzle.

#define H_    181
#define W_    360
#define CIN_  32
#define COUT_ 64
#define K_    4
#define NNZ_  9
#define NNZ1_ 4
#define HW_   (H_*W_)
#define NT_   (NNZ1_*K_*NNZ_)   // 144 composed taps per output row
#define HWPB_ 180               // pixels per block (half row)
#define TPB_  256
#define ZP_   33                // padded z stride (kills 32-bank aliasing)
#define NLOG_ 362               // logical blocks (181 rows x 2 halves)

__global__ __launch_bounds__(TPB_) void sepconv_fused(
    const float* __restrict__ x, const float* __restrict__ quad_w,
    const float* __restrict__ vals, const int* __restrict__ hi,
    const int* __restrict__ wi, const float* __restrict__ w_depth,
    const float* __restrict__ vals1, const int* __restrict__ hi1,
    const int* __restrict__ wi1, const float* __restrict__ w_point,
    const float* __restrict__ bias, float* __restrict__ out)
{
    // XCD swizzle: dispatch round-robins bid%8 across XCDs; give each XCD a
    // contiguous band of logical indices so the 5-row halo stays L2-local.
    const int bid = blockIdx.x;
    const int L   = (bid & 7) * 46 + (bid >> 3);   // 8 bands of 46
    if (L >= NLOG_) return;                         // 6 pad blocks exit whole
    const int h    = L >> 1;
    const int half = L & 1;
    const int tid  = threadIdx.x;

    __shared__ float Tval[NT_];
    __shared__ int   Tbin[NT_];
    __shared__ float S[K_][25];
    __shared__ float C[CIN_][25];
    __shared__ float zsm[HWPB_ * ZP_];

    // --- coef build: decode 144 composed taps -------------------------------
    if (tid < NT_) {
        const int a   = tid / 36;
        const int rem = tid - a * 36;
        const int k   = rem / 9;
        const int j   = rem - k * 9;
        const int e1  = h * NNZ1_ + a;
        const int m   = hi1[e1];
        const int w1  = wi1[e1];
        const int d1  = (w1 == 1) ? 1 : ((w1 == 0) ? 0 : -1);
        const int e   = (k * H_ + m) * NNZ_ + j;
        const int r   = hi[e];
        const int w0  = wi[e];
        const int d   = (w0 == 1) ? 1 : ((w0 == 0) ? 0 : -1);
        Tval[tid] = vals1[e1] * quad_w[m] * vals[e] * quad_w[r];
        Tbin[tid] = (r - h + 2) * 5 + (d1 + d + 2);
    }
    __syncthreads();

    // S[k][bin]: parallel read-only scans (no LDS RMW chain)
    if (tid < K_ * 25) {
        const int k   = tid / 25;
        const int bin = tid - k * 25;
        float s = 0.f;
        #pragma unroll
        for (int a = 0; a < NNZ1_; ++a)
            #pragma unroll
            for (int j = 0; j < NNZ_; ++j) {
                const int t2 = a * 36 + k * 9 + j;
                if (Tbin[t2] == bin) s += Tval[t2];
            }
        S[k][bin] = s;
    }
    __syncthreads();

    // C[c][bin] = w_depth[c,:] . S[:,bin]
    for (int item = tid; item < CIN_ * 25; item += TPB_) {
        const int c   = item / 25;
        const int bin = item - c * 25;
        float acc = 0.f;
        #pragma unroll
        for (int k = 0; k < K_; ++k) acc += w_depth[c * K_ + k] * S[k][bin];
        C[c][bin] = acc;
    }
    __syncthreads();

    // --- Phase A: depthwise 5x5 stencil, 4 px x 8 ch per thread -------------
    // thread = (px-group pg, ch-group chg); float4 row loads, registers slide.
    if (tid < HWPB_) {                  // 45 pg x 4 chg
        const int chg = tid & 3;
        const int pg  = tid >> 2;
        const int bw  = half * HWPB_ + pg * 4;      // first of 4 pixels
        const int cA  = (bw + W_ - 4) % W_;         // aligned float4 chunks
        const int cB  = bw;
        const int cC  = (bw + 4) % W_;

        int rowoff[5];
        #pragma unroll
        for (int rb = 0; rb < 5; ++rb) {
            int r = h - 2 + rb;
            r = (r < 0) ? 0 : ((r > H_ - 1) ? H_ - 1 : r);
            rowoff[rb] = r * W_;
        }

        #pragma unroll 2
        for (int cc = 0; cc < 8; ++cc) {
            const int c = chg * 8 + cc;
            const float* xc = x + c * HW_;
            const float* Cc = &C[c][0];
            float a0 = 0.f, a1 = 0.f, a2 = 0.f, a3 = 0.f;
            #pragma unroll
            for (int rb = 0; rb < 5; ++rb) {
                const float* xr = xc + rowoff[rb];
                const float4 vA = *(const float4*)(xr + cA);
                const float4 vB = *(const float4*)(xr + cB);
                const float4 vC = *(const float4*)(xr + cC);
                const float k0 = Cc[rb * 5 + 0], k1 = Cc[rb * 5 + 1],
                            k2 = Cc[rb * 5 + 2], k3 = Cc[rb * 5 + 3],
                            k4 = Cc[rb * 5 + 4];
                a0 += k0 * vA.z + k1 * vA.w + k2 * vB.x + k3 * vB.y + k4 * vB.z;
                a1 += k0 * vA.w + k1 * vB.x + k2 * vB.y + k3 * vB.z + k4 * vB.w;
                a2 += k0 * vB.x + k1 * vB.y + k2 * vB.z + k3 * vB.w + k4 * vC.x;
                a3 += k0 * vB.y + k1 * vB.z + k2 * vB.w + k3 * vC.x + k4 * vC.y;
            }
            const int p0 = pg * 4;
            zsm[(p0 + 0) * ZP_ + c] = a0;
            zsm[(p0 + 1) * ZP_ + c] = a1;
            zsm[(p0 + 2) * ZP_ + c] = a2;
            zsm[(p0 + 3) * ZP_ + c] = a3;
        }
    }
    __syncthreads();

    // --- Phase B: 32->64 GEMV per pixel, z in registers ---------------------
    if (tid < HWPB_) {
        float z[CIN_];
        #pragma unroll
        for (int c = 0; c < CIN_; ++c) z[c] = zsm[tid * ZP_ + c];

        const int w = half * HWPB_ + tid;
        float* op = out + h * W_ + w;
        #pragma unroll 4
        for (int o = 0; o < COUT_; ++o) {
            float acc = bias[o];
            #pragma unroll
            for (int c = 0; c < CIN_; ++c) acc += w_point[o * CIN_ + c] * z[c];
            op[o * HW_] = acc;
        }
    }
}

extern "C" void kernel_launch(void* const* d_in, const int* in_sizes, int n_in,
                              void* d_out, int out_size, void* d_ws, size_t ws_size,
                              hipStream_t stream) {
    const float* x       = (const float*)d_in[0];
    const float* quad_w  = (const float*)d_in[1];
    const float* vals    = (const float*)d_in[2];
    // d_in[3] = seg  (unused; tap membership implied by entry ordering)
    const int*   hi      = (const int*)d_in[4];
    const int*   wi      = (const int*)d_in[5];
    const float* w_depth = (const float*)d_in[6];
    const float* vals1   = (const float*)d_in[7];
    // d_in[8] = seg1 (unused)
    const int*   hi1     = (const int*)d_in[9];
    const int*   wi1     = (const int*)d_in[10];
    const float* w_point = (const float*)d_in[11];
    const float* bias    = (const float*)d_in[12];
    // d_in[13] = K (compile-time constant 4)

    sepconv_fused<<<368, TPB_, 0, stream>>>(
        x, quad_w, vals, hi, wi, w_depth, vals1, hi1, wi1,
        w_point, bias, (float*)d_out);
}

// Round 4
// 125.719 us; speedup vs baseline: 1.0801x; 1.0801x over previous
//
#include <hip/hip_runtime.h>

// SepConv on sphere, round 4: two highly-parallel kernels through d_ws.
// Algebra (verified absmax 0.0 in R2/R3): the chain
//   x -> *qw -> DISCO(K=4,9tap) -> depth-mix -> *qw -> DISCO(K=1,4tap) -> 1x1
// composes into one 5x5 clip/wrap stencil with per-(c,h) coefs
// C[c][25] = w_depth[c,:] . S[4][25] (S channel-independent, 144 taps),
// then a 32->64 pointwise GEMV.
//
// R4 fix (R3 was parallelism-starved: 362 blocks, VALUBusy 16%, occ 12%):
// K1 grid 1448 blocks (h-band x cseg), K2 grid 510 blocks; no idle threads,
// short per-thread chains.

#define H_    181
#define W_    360
#define CIN_  32
#define COUT_ 64
#define K_    4
#define NNZ_  9
#define NNZ1_ 4
#define HW_   (H_*W_)
#define NT_   (NNZ1_*K_*NNZ_)   // 144 composed taps per output row
#define PXT_  128               // K2 pixel tile

// ---------------------------------------------------------------------------
// K1: z[c,h,w] = sum_bin C[c,h,bin] * x[c, cliprow(h,bin), wrapcol(w,bin)]
// grid (184, 8): blockIdx.x -> swizzled h (8 XCD bands of 23 rows),
// blockIdx.y = cseg (4 channels). 256 threads; item = (c4, 4-px group).
// ---------------------------------------------------------------------------
__global__ __launch_bounds__(256) void sepconv_stencil(
    const float* __restrict__ x, const float* __restrict__ quad_w,
    const float* __restrict__ vals, const int* __restrict__ hi,
    const int* __restrict__ wi, const float* __restrict__ w_depth,
    const float* __restrict__ vals1, const int* __restrict__ hi1,
    const int* __restrict__ wi1, float* __restrict__ z)
{
    // 184 % 8 == 0, so XCD = blockIdx.x % 8 regardless of blockIdx.y:
    // band swizzle keeps each XCD on 23 contiguous rows (halo L2-local).
    const int bx = blockIdx.x;
    const int h  = (bx & 7) * 23 + (bx >> 3);
    if (h >= H_) return;                      // 3 pad blocks, uniform exit
    const int cseg = blockIdx.y;              // channels cseg*4 .. cseg*4+3
    const int tid  = threadIdx.x;

    __shared__ float Tval[NT_];
    __shared__ int   Tbin[NT_];
    __shared__ float S[K_][25];
    __shared__ float C[4][25];

    // decode 144 composed taps for this h
    if (tid < NT_) {
        const int a   = tid / 36;
        const int rem = tid - a * 36;
        const int k   = rem / 9;
        const int j   = rem - k * 9;
        const int e1  = h * NNZ1_ + a;
        const int m   = hi1[e1];
        const int w1  = wi1[e1];
        const int d1  = (w1 == 1) ? 1 : ((w1 == 0) ? 0 : -1);
        const int e   = (k * H_ + m) * NNZ_ + j;
        const int r   = hi[e];
        const int w0  = wi[e];
        const int d   = (w0 == 1) ? 1 : ((w0 == 0) ? 0 : -1);
        Tval[tid] = vals1[e1] * quad_w[m] * vals[e] * quad_w[r];
        Tbin[tid] = (r - h + 2) * 5 + (d1 + d + 2);   // in [0,25)
    }
    __syncthreads();

    // S[k][bin]: parallel read-only scans
    if (tid < K_ * 25) {
        const int k   = tid / 25;
        const int bin = tid - k * 25;
        float s = 0.f;
        #pragma unroll
        for (int a = 0; a < NNZ1_; ++a)
            #pragma unroll
            for (int j = 0; j < NNZ_; ++j) {
                const int t2 = a * 36 + k * 9 + j;
                if (Tbin[t2] == bin) s += Tval[t2];
            }
        S[k][bin] = s;
    }
    __syncthreads();

    // C[c4][bin] for this block's 4 channels
    if (tid < 4 * 25) {
        const int c4  = tid / 25;
        const int bin = tid - c4 * 25;
        const int c   = cseg * 4 + c4;
        float acc = 0.f;
        #pragma unroll
        for (int k = 0; k < K_; ++k) acc += w_depth[c * K_ + k] * S[k][bin];
        C[c4][bin] = acc;
    }
    __syncthreads();

    int rowoff[5];
    #pragma unroll
    for (int rb = 0; rb < 5; ++rb) {
        int r = h - 2 + rb;
        r = (r < 0) ? 0 : ((r > H_ - 1) ? H_ - 1 : r);
        rowoff[rb] = r * W_;
    }

    // 4 channels x 90 four-pixel groups = 360 items
    for (int item = tid; item < 4 * 90; item += 256) {
        const int c4 = item / 90;
        const int g  = item - c4 * 90;
        const int c  = cseg * 4 + c4;
        const int bw = g * 4;
        const int cA = (bw + W_ - 4) % W_;
        const int cB = bw;
        const int cC = (bw + 4) % W_;
        const float* xc = x + c * HW_;
        const float* Cc = &C[c4][0];

        float a0 = 0.f, a1 = 0.f, a2 = 0.f, a3 = 0.f;
        #pragma unroll
        for (int rb = 0; rb < 5; ++rb) {
            const float* xr = xc + rowoff[rb];
            const float4 vA = *(const float4*)(xr + cA);
            const float4 vB = *(const float4*)(xr + cB);
            const float4 vC = *(const float4*)(xr + cC);
            const float k0 = Cc[rb * 5 + 0], k1 = Cc[rb * 5 + 1],
                        k2 = Cc[rb * 5 + 2], k3 = Cc[rb * 5 + 3],
                        k4 = Cc[rb * 5 + 4];
            a0 += k0 * vA.z + k1 * vA.w + k2 * vB.x + k3 * vB.y + k4 * vB.z;
            a1 += k0 * vA.w + k1 * vB.x + k2 * vB.y + k3 * vB.z + k4 * vB.w;
            a2 += k0 * vB.x + k1 * vB.y + k2 * vB.z + k3 * vB.w + k4 * vC.x;
            a3 += k0 * vB.y + k1 * vB.z + k2 * vB.w + k3 * vC.x + k4 * vC.y;
        }
        float4 r4; r4.x = a0; r4.y = a1; r4.z = a2; r4.w = a3;
        *(float4*)(z + c * HW_ + h * W_ + bw) = r4;
    }
}

// ---------------------------------------------------------------------------
// K2: out[o,p] = bias[o] + sum_c w_point[o,c] * z[c,p], p = flat pixel.
// Block = 128-px tile staged in LDS; thread = (px, o-half) -> 32 o x 32 c.
// ---------------------------------------------------------------------------
__global__ __launch_bounds__(256) void sepconv_pointwise(
    const float* __restrict__ z, const float* __restrict__ w_point,
    const float* __restrict__ bias, float* __restrict__ out)
{
    const int p0  = blockIdx.x * PXT_;
    const int tid = threadIdx.x;

    __shared__ float zs[CIN_][PXT_];
    for (int i = tid; i < CIN_ * PXT_; i += 256) {
        const int c = i >> 7;
        const int j = i & (PXT_ - 1);
        const int p = p0 + j;
        zs[c][j] = (p < HW_) ? z[c * HW_ + p] : 0.f;
    }
    __syncthreads();

    const int j  = tid & (PXT_ - 1);
    const int oh = tid >> 7;            // o in [oh*32, oh*32+32)
    const int p  = p0 + j;

    float zr[CIN_];
    #pragma unroll
    for (int c = 0; c < CIN_; ++c) zr[c] = zs[c][j];   // 2-way LDS, free

    if (p < HW_) {
        const float* wp = w_point + oh * 32 * CIN_;
        float* op = out + oh * 32 * HW_ + p;
        #pragma unroll 8
        for (int oo = 0; oo < 32; ++oo) {
            float acc = bias[oh * 32 + oo];
            #pragma unroll
            for (int c = 0; c < CIN_; ++c) acc += wp[oo * CIN_ + c] * zr[c];
            op[oo * HW_] = acc;
        }
    }
}

extern "C" void kernel_launch(void* const* d_in, const int* in_sizes, int n_in,
                              void* d_out, int out_size, void* d_ws, size_t ws_size,
                              hipStream_t stream) {
    const float* x       = (const float*)d_in[0];
    const float* quad_w  = (const float*)d_in[1];
    const float* vals    = (const float*)d_in[2];
    // d_in[3] = seg  (unused; tap membership implied by entry ordering)
    const int*   hi      = (const int*)d_in[4];
    const int*   wi      = (const int*)d_in[5];
    const float* w_depth = (const float*)d_in[6];
    const float* vals1   = (const float*)d_in[7];
    // d_in[8] = seg1 (unused)
    const int*   hi1     = (const int*)d_in[9];
    const int*   wi1     = (const int*)d_in[10];
    const float* w_point = (const float*)d_in[11];
    const float* bias    = (const float*)d_in[12];
    // d_in[13] = K (compile-time constant 4)

    float* z = (float*)d_ws;   // 32*181*360 floats = 8.34 MB

    sepconv_stencil<<<dim3(184, 8), 256, 0, stream>>>(
        x, quad_w, vals, hi, wi, w_depth, vals1, hi1, wi1, z);
    sepconv_pointwise<<<(HW_ + PXT_ - 1) / PXT_, 256, 0, stream>>>(
        z, w_point, bias, (float*)d_out);
}